// Round 4
// baseline (73.488 us; speedup 1.0000x reference)
//
#include <hip/hip_runtime.h>

#define ODE_UNFOLDS 6
#define LTC_EPS 1e-8f

// One lane per (batch b, pair j<d): the lane owns BOTH units a=j and c=j+d.
// The pair's two recurrences are independent twin chains -> the scheduler can
// interleave them to hide all VALU/trans latency, and there is NO cross-lane
// exchange (the R2 DPP + its hazard stalls are gone).
//
// Per unfold, per unit, normalized-sigmoid rcps are eliminated by multiplying
// num/den through by P=(1+e_s)(1+e_c):
//   den' = (db+Ws+Wc) + (db+Wc)e_s + (db+Ws)e_c + db*e_s*e_c
//   num' = (t+WEs+WEc) + (t+WEc)e_s + (t+WEs)e_c + t*e_s*e_c,  t=cm*v+nb
// exp args come from (A*num)*r + C so the v=num*r mul stays off the cycle.
// 4 exp + 2 rcp per unfold for the pair, all constants folded, exp2-domain.

__global__ __launch_bounds__(64)
void ltc_pair2_kernel(const float* __restrict__ inputs,
                      const float* __restrict__ input_w, const float* __restrict__ input_b,
                      const float* __restrict__ output_w, const float* __restrict__ output_b,
                      const float* __restrict__ gleak, const float* __restrict__ vleak,
                      const float* __restrict__ cm,
                      const float* __restrict__ w, const float* __restrict__ mu,
                      const float* __restrict__ sigma, const float* __restrict__ erev,
                      const float* __restrict__ sw, const float* __restrict__ smu,
                      const float* __restrict__ ssig, const float* __restrict__ serev,
                      float* __restrict__ out,
                      int B, int T, int d)
{
    const int tid = blockIdx.x * blockDim.x + threadIdx.x;
    if (tid >= B * d) return;
    const int b = tid / d;
    const int j = tid - b * d;
    const int units = 2 * d;
    const int p = j + d;

    const float LOG2E = 1.4426950408889634f;

    // ---- unit A = j : self synapse j->j, incoming cross p->j
    float AsA, CsA, WsA, WEsA, AcA, CcA, WcA, WEcA;
    {
        int i = j * units + j;
        float sg = sigma[i], m = mu[i];
        AsA = -sg * LOG2E; CsA = m * sg * LOG2E; WsA = w[i]; WEsA = WsA * erev[i];
        i = p * units + j;                    // src p -> dst j, evaluated at vB
        sg = sigma[i]; m = mu[i];
        AcA = -sg * LOG2E; CcA = m * sg * LOG2E; WcA = w[i]; WEcA = WcA * erev[i];
    }
    // ---- unit C = p : self synapse p->p, incoming cross j->p
    float AsB, CsB, WsB, WEsB, AcB, CcB, WcB, WEcB;
    {
        int i = p * units + p;
        float sg = sigma[i], m = mu[i];
        AsB = -sg * LOG2E; CsB = m * sg * LOG2E; WsB = w[i]; WEsB = WsB * erev[i];
        i = j * units + p;                    // src j -> dst p, evaluated at vA
        sg = sigma[i]; m = mu[i];
        AcB = -sg * LOG2E; CcB = m * sg * LOG2E; WcB = w[i]; WEcB = WcB * erev[i];
    }
    const float WsumA = WsA + WcA,  WEsumA = WEsA + WEcA;
    const float WsumB = WsB + WcB,  WEsumB = WEsB + WEcB;

    // ---- sensory j -> A and j -> B, input affine folded in
    float siAA, siCA, sWA, sWEA, siAB, siCB, sWB, sWEB;
    {
        const float iw = input_w[j], ib = input_b[j];
        int i = j * units + j;
        float sg = ssig[i], m = smu[i];
        float sA = -sg * LOG2E, sC = m * sg * LOG2E;
        siAA = iw * sA; siCA = ib * sA + sC; sWA = sw[i]; sWEA = sWA * serev[i];
        i = j * units + p;
        sg = ssig[i]; m = smu[i];
        sA = -sg * LOG2E; sC = m * sg * LOG2E;
        siAB = iw * sA; siCB = ib * sA + sC; sWB = sw[i]; sWEB = sWB * serev[i];
    }

    const float cmA = cm[j] * (float)ODE_UNFOLDS;
    const float cmB = cm[p] * (float)ODE_UNFOLDS;
    const float glA = gleak[j], glB = gleak[p];
    const float gvA = glA * vleak[j], gvB = glB * vleak[p];
    const float den0A = cmA + glA + LTC_EPS;
    const float den0B = cmB + glB + LTC_EPS;

    const float* __restrict__ xin = inputs + (size_t)b * T * d + j;

    // recurrence state per unit: v = num * r, r = rcp(den)
    float numA = 0.f, rA = 1.f, numB = 0.f, rB = 1.f;

    const int TU = 4;
    float xbuf[TU];
#pragma unroll
    for (int k = 0; k < TU; ++k) xbuf[k] = xin[(size_t)k * d];

    for (int g = 0; g < T; g += TU) {
        float xnext[TU];
        if (g + TU < T) {
#pragma unroll
            for (int k = 0; k < TU; ++k) xnext[k] = xin[(size_t)(g + TU + k) * d];
        } else {
#pragma unroll
            for (int k = 0; k < TU; ++k) xnext[k] = 0.f;
        }

#pragma unroll
        for (int k = 0; k < TU; ++k) {
            // ---- sensory (x-dependent only, off the recurrence cycle)
            const float eA_ = __builtin_amdgcn_exp2f(fmaf(xbuf[k], siAA, siCA));
            const float eB_ = __builtin_amdgcn_exp2f(fmaf(xbuf[k], siAB, siCB));
            const float ssA = __builtin_amdgcn_rcpf(1.f + eA_);
            const float ssB = __builtin_amdgcn_rcpf(1.f + eB_);
            const float nbA = fmaf(sWEA, ssA, gvA);
            const float dbA = fmaf(sWA,  ssA, den0A);
            const float nbB = fmaf(sWEB, ssB, gvB);
            const float dbB = fmaf(sWB,  ssB, den0B);
            const float K0A = dbA + WsumA, KsA = dbA + WcA, KxA = dbA + WsA;
            const float K0B = dbB + WsumB, KsB = dbB + WcB, KxB = dbB + WsB;

#pragma unroll
            for (int uu = 0; uu < ODE_UNFOLDS; ++uu) {
                // off-cycle values
                const float vA = numA * rA;
                const float vB = numB * rB;
                const float tA = fmaf(cmA, vA, nbA);
                const float tB = fmaf(cmB, vB, nbB);

                // exp args directly from (num, r): arg = (A*num)*r + C
                const float argsA = fmaf(AsA * numA, rA, CsA);
                const float argsB = fmaf(AsB * numB, rB, CsB);
                const float argcA = fmaf(AcA * numB, rB, CcA);  // p->j at vB
                const float argcB = fmaf(AcB * numA, rA, CcB);  // j->p at vA

                const float esA = __builtin_amdgcn_exp2f(argsA);
                const float esB = __builtin_amdgcn_exp2f(argsB);
                const float ecA = __builtin_amdgcn_exp2f(argcA);
                const float ecB = __builtin_amdgcn_exp2f(argcB);

                const float mA = esA * ecA;
                const float mB = esB * ecB;

                float dA = fmaf(KsA, esA, K0A);
                dA = fmaf(KxA, ecA, dA);
                dA = fmaf(dbA, mA, dA);
                float dB = fmaf(KsB, esB, K0B);
                dB = fmaf(KxB, ecB, dB);
                dB = fmaf(dbB, mB, dB);

                float nA = fmaf(tA + WEcA, esA, tA + WEsumA);
                nA = fmaf(tA + WEsA, ecA, nA);
                nA = fmaf(tA, mA, nA);
                float nB = fmaf(tB + WEcB, esB, tB + WEsumB);
                nB = fmaf(tB + WEsB, ecB, nB);
                nB = fmaf(tB, mB, nB);

                numA = nA; rA = __builtin_amdgcn_rcpf(dA);
                numB = nB; rB = __builtin_amdgcn_rcpf(dB);
            }
        }

#pragma unroll
        for (int k = 0; k < TU; ++k) xbuf[k] = xnext[k];
    }

    const float vA = numA * rA;
    out[(size_t)b * d + j] = fmaf(vA, output_w[j], output_b[j]);
}

extern "C" void kernel_launch(void* const* d_in, const int* in_sizes, int n_in,
                              void* d_out, int out_size, void* d_ws, size_t ws_size,
                              hipStream_t stream) {
    const float* inputs   = (const float*)d_in[0];
    const float* input_w  = (const float*)d_in[1];
    const float* input_b  = (const float*)d_in[2];
    const float* output_w = (const float*)d_in[3];
    const float* output_b = (const float*)d_in[4];
    const float* gleak    = (const float*)d_in[5];
    const float* vleak    = (const float*)d_in[6];
    const float* cm       = (const float*)d_in[7];
    const float* w        = (const float*)d_in[8];
    const float* mu       = (const float*)d_in[9];
    const float* sigma    = (const float*)d_in[10];
    const float* erev     = (const float*)d_in[11];
    const float* sw       = (const float*)d_in[12];
    const float* smu      = (const float*)d_in[13];
    const float* ssig     = (const float*)d_in[14];
    const float* serev    = (const float*)d_in[15];
    float* out = (float*)d_out;

    const int d = in_sizes[1];            // input_w has shape (d,)
    const int B = out_size / d;           // out is (B, d)
    const int T = in_sizes[0] / (B * d);  // inputs is (B, T, d)

    const int total = B * d;              // one thread per (b, pair)
    const int block = 64;
    const int grid = (total + block - 1) / block;
    ltc_pair2_kernel<<<grid, block, 0, stream>>>(
        inputs, input_w, input_b, output_w, output_b,
        gleak, vleak, cm, w, mu, sigma, erev,
        sw, smu, ssig, serev, out, B, T, d);
}

// Round 5
// 42.634 us; speedup vs baseline: 1.7237x; 1.7237x over previous
//
#include <hip/hip_runtime.h>

#define ODE_UNFOLDS 6
#define LTC_EPS 1e-8f

// One lane per (batch b, unit u); adjacent lanes hold the coupled pair
// {j, j+d}. State is (num, r) with v = num*r, r = rcp(den).
//
// Per unfold (exact algebra, num/den scaled by P=(1+e_s)(1+e_x)):
//   den' = K0 + Ks*e_s + Kx*e_x + db*e_s*e_x
//   num' = n0 + c1*e_s + c2*e_x +  t*e_s*e_x,   t = cm*v + nb
// factored in Horner form around the LATE input e_x (partner's exp arrives
// ~16cy after own e_s via DPP):
//   den' = (K0 + Ks*e_s) + e_x*(Kx + db*e_s)     <- depth-1 in e_x
//   num' = (n0 + c1*e_s) + e_x*(c2 +  t*e_s)
// The 4 inner fmas issue while waiting for e_x. exp args come from
// (A*num)*r + C so the v=num*r mul stays off the recurrence cycle.

__device__ __forceinline__ float swap_pair(float x) {
    // quad_perm [1,0,3,2] : lane XOR 1, full-rate v_mov_b32 dpp
    return __int_as_float(
        __builtin_amdgcn_mov_dpp(__float_as_int(x), 0xB1, 0xF, 0xF, true));
}

__global__ __launch_bounds__(64)
void ltc_lane_kernel(const float* __restrict__ inputs,
                     const float* __restrict__ input_w, const float* __restrict__ input_b,
                     const float* __restrict__ output_w, const float* __restrict__ output_b,
                     const float* __restrict__ gleak, const float* __restrict__ vleak,
                     const float* __restrict__ cm,
                     const float* __restrict__ w, const float* __restrict__ mu,
                     const float* __restrict__ sigma, const float* __restrict__ erev,
                     const float* __restrict__ sw, const float* __restrict__ smu,
                     const float* __restrict__ ssig, const float* __restrict__ serev,
                     float* __restrict__ out,
                     int B, int T, int d)
{
    const int tid = blockIdx.x * blockDim.x + threadIdx.x;
    const int units = 2 * d;
    if (tid >= B * units) return;

    const int pairIdx = tid >> 1;
    const int h = tid & 1;                 // 0 -> unit j, 1 -> unit j+d
    const int b = pairIdx / d;
    const int j = pairIdx - b * d;
    const int u  = j + h * d;              // my unit
    const int pu = j + (1 - h) * d;        // partner unit

    const float LOG2E = 1.4426950408889634f;

    // self synapse u->u
    float A_s, C_s, W_s, WE_s;
    {
        int i = u * units + u;
        float sg = sigma[i], m = mu[i];
        A_s = -sg * LOG2E; C_s = m * sg * LOG2E;
        W_s = w[i]; WE_s = W_s * erev[i];
    }
    // incoming cross synapse pu->u: weights only (partner computes its exp)
    float W_c, WE_c;
    {
        int i = pu * units + u;
        W_c = w[i]; WE_c = W_c * erev[i];
    }
    // outgoing cross synapse u->pu: exp consts only
    float A_o, C_o;
    {
        int i = u * units + pu;
        float sg = sigma[i], m = mu[i];
        A_o = -sg * LOG2E; C_o = m * sg * LOG2E;
    }
    const float Wsum  = W_s + W_c;
    const float WEsum = WE_s + WE_c;

    // sensory synapse j -> u, input affine folded in
    float siA, siC, sW, sWE;
    {
        int i = j * units + u;
        float sg = ssig[i], m = smu[i];
        float sA = -sg * LOG2E, sC = m * sg * LOG2E;
        const float iw = input_w[j], ib = input_b[j];
        siA = iw * sA; siC = ib * sA + sC;
        sW = sw[i]; sWE = sW * serev[i];
    }

    const float cmu = cm[u] * (float)ODE_UNFOLDS;
    const float gl  = gleak[u];
    const float gv  = gl * vleak[u];
    const float den0 = cmu + gl + LTC_EPS;

    const float* __restrict__ xin = inputs + (size_t)b * T * d + j;

    // recurrence state: v = num * r
    float num = 0.f, r = 1.f;

    const int TU = 4;
    float xbuf[TU];
#pragma unroll
    for (int k = 0; k < TU; ++k) xbuf[k] = xin[(size_t)k * d];

    for (int g = 0; g < T; g += TU) {
        float xnext[TU];
        if (g + TU < T) {
#pragma unroll
            for (int k = 0; k < TU; ++k) xnext[k] = xin[(size_t)(g + TU + k) * d];
        } else {
#pragma unroll
            for (int k = 0; k < TU; ++k) xnext[k] = 0.f;
        }

#pragma unroll
        for (int k = 0; k < TU; ++k) {
            // per-timestep bases (x-dependent only, off the recurrence cycle)
            const float es_ = __builtin_amdgcn_exp2f(fmaf(xbuf[k], siA, siC));
            const float ss  = __builtin_amdgcn_rcpf(1.f + es_);
            const float nb  = fmaf(sWE, ss, gv);
            const float db  = fmaf(sW,  ss, den0);
            const float K0  = db + Wsum;
            const float Ks  = db + W_c;   // coefficient of e_s
            const float Kx  = db + W_s;   // coefficient of e_x

#pragma unroll
            for (int uu = 0; uu < ODE_UNFOLDS; ++uu) {
                const float v    = num * r;              // off critical cycle
                const float ts   = A_s * num;            // hides under rcp
                const float to   = A_o * num;
                const float args = fmaf(ts, r, C_s);     // = A_s*v + C_s
                const float argo = fmaf(to, r, C_o);
                const float es = __builtin_amdgcn_exp2f(args);
                const float eo = __builtin_amdgcn_exp2f(argo);
                const float ex = swap_pair(eo);          // partner's exp (late)

                const float t  = fmaf(cmu, v, nb);
                const float c1 = t + WE_c;
                const float c2 = t + WE_s;
                const float n0 = t + WEsum;

                // es-only inner stage (issues while ex is in flight)
                const float P1 = fmaf(Ks, es, K0);
                const float P2 = fmaf(db, es, Kx);
                const float Q1 = fmaf(c1, es, n0);
                const float Q2 = fmaf(t,  es, c2);

                // depth-1 final stage in ex
                const float dsum = fmaf(P2, ex, P1);
                const float nsum = fmaf(Q2, ex, Q1);

                num = nsum;
                r = __builtin_amdgcn_rcpf(dsum);
            }
        }

#pragma unroll
        for (int k = 0; k < TU; ++k) xbuf[k] = xnext[k];
    }

    if (h == 0) {
        const float v = num * r;
        out[(size_t)b * d + j] = fmaf(v, output_w[j], output_b[j]);
    }
}

extern "C" void kernel_launch(void* const* d_in, const int* in_sizes, int n_in,
                              void* d_out, int out_size, void* d_ws, size_t ws_size,
                              hipStream_t stream) {
    const float* inputs   = (const float*)d_in[0];
    const float* input_w  = (const float*)d_in[1];
    const float* input_b  = (const float*)d_in[2];
    const float* output_w = (const float*)d_in[3];
    const float* output_b = (const float*)d_in[4];
    const float* gleak    = (const float*)d_in[5];
    const float* vleak    = (const float*)d_in[6];
    const float* cm       = (const float*)d_in[7];
    const float* w        = (const float*)d_in[8];
    const float* mu       = (const float*)d_in[9];
    const float* sigma    = (const float*)d_in[10];
    const float* erev     = (const float*)d_in[11];
    const float* sw       = (const float*)d_in[12];
    const float* smu      = (const float*)d_in[13];
    const float* ssig     = (const float*)d_in[14];
    const float* serev    = (const float*)d_in[15];
    float* out = (float*)d_out;

    const int d = in_sizes[1];            // input_w has shape (d,)
    const int B = out_size / d;           // out is (B, d)
    const int T = in_sizes[0] / (B * d);  // inputs is (B, T, d)

    const int total = B * 2 * d;          // one thread per (b, unit)
    const int block = 64;
    const int grid = (total + block - 1) / block;
    ltc_lane_kernel<<<grid, block, 0, stream>>>(
        inputs, input_w, input_b, output_w, output_b,
        gleak, vleak, cm, w, mu, sigma, erev,
        sw, smu, ssig, serev, out, B, T, d);
}

// Round 6
// 41.308 us; speedup vs baseline: 1.7790x; 1.0321x over previous
//
#include <hip/hip_runtime.h>

#define ODE_UNFOLDS 6
#define LTC_EPS 1e-8f

// One lane per (batch b, unit u); adjacent lanes hold the coupled pair {j,j+d}.
// State: (num, r), v = num*r. Per unfold (exact, num/den scaled through by
// P=(1+e_s)(1+e_x)):
//   den' = (K0 + Ks*es) + ex*(Kx + db*es)
//   num' = (n0 + c1*es) + ex*(c2 + t*es)
// with t,c1,c2,n0 each a SINGLE fma off r: fma(cmu*num, r, {nb,g1,g2,g0}),
// g0=nb+WEsum, g1=nb+WE_c, g2=nb+WE_s precomputed per timestep.
// The per-timestep base block (sensory sigmoid chain, 2 trans deep) is
// software-pipelined ONE TIMESTEP AHEAD so it hides under unfold stalls.

__device__ __forceinline__ float swap_pair(float x) {
    // quad_perm [1,0,3,2] : lane XOR 1, full-rate v_mov_b32 dpp
    return __int_as_float(
        __builtin_amdgcn_mov_dpp(__float_as_int(x), 0xB1, 0xF, 0xF, true));
}

struct Base { float nb, db, K0, Ks, Kx, g0, g1, g2; };

__global__ __launch_bounds__(64)
void ltc_lane_kernel(const float* __restrict__ inputs,
                     const float* __restrict__ input_w, const float* __restrict__ input_b,
                     const float* __restrict__ output_w, const float* __restrict__ output_b,
                     const float* __restrict__ gleak, const float* __restrict__ vleak,
                     const float* __restrict__ cm,
                     const float* __restrict__ w, const float* __restrict__ mu,
                     const float* __restrict__ sigma, const float* __restrict__ erev,
                     const float* __restrict__ sw, const float* __restrict__ smu,
                     const float* __restrict__ ssig, const float* __restrict__ serev,
                     float* __restrict__ out,
                     int B, int T, int d)
{
    const int tid = blockIdx.x * blockDim.x + threadIdx.x;
    const int units = 2 * d;
    if (tid >= B * units) return;

    const int pairIdx = tid >> 1;
    const int h = tid & 1;                 // 0 -> unit j, 1 -> unit j+d
    const int b = pairIdx / d;
    const int j = pairIdx - b * d;
    const int u  = j + h * d;              // my unit
    const int pu = j + (1 - h) * d;        // partner unit

    const float LOG2E = 1.4426950408889634f;

    // self synapse u->u
    float A_s, C_s, W_s, WE_s;
    {
        int i = u * units + u;
        float sg = sigma[i], m = mu[i];
        A_s = -sg * LOG2E; C_s = m * sg * LOG2E;
        W_s = w[i]; WE_s = W_s * erev[i];
    }
    // incoming cross synapse pu->u (partner computes its exp, we get it via DPP)
    float W_c, WE_c;
    {
        int i = pu * units + u;
        W_c = w[i]; WE_c = W_c * erev[i];
    }
    // outgoing cross synapse u->pu
    float A_o, C_o;
    {
        int i = u * units + pu;
        float sg = sigma[i], m = mu[i];
        A_o = -sg * LOG2E; C_o = m * sg * LOG2E;
    }
    const float Wsum  = W_s + W_c;
    const float WEsum = WE_s + WE_c;

    // sensory synapse j -> u, input affine folded in
    float siA, siC, sW, sWE;
    {
        int i = j * units + u;
        float sg = ssig[i], m = smu[i];
        float sA = -sg * LOG2E, sC = m * sg * LOG2E;
        const float iw = input_w[j], ib = input_b[j];
        siA = iw * sA; siC = ib * sA + sC;
        sW = sw[i]; sWE = sW * serev[i];
    }

    const float cmu = cm[u] * (float)ODE_UNFOLDS;
    const float gl  = gleak[u];
    const float gv  = gl * vleak[u];
    const float den0 = cmu + gl + LTC_EPS;

    const float* __restrict__ xin = inputs + (size_t)b * T * d + j;

    auto make_base = [&](float x) -> Base {
        Base bb;
        const float e  = __builtin_amdgcn_exp2f(fmaf(x, siA, siC));
        const float ss = __builtin_amdgcn_rcpf(1.f + e);
        bb.nb = fmaf(sWE, ss, gv);
        bb.db = fmaf(sW,  ss, den0);
        bb.K0 = bb.db + Wsum;
        bb.Ks = bb.db + W_c;
        bb.Kx = bb.db + W_s;
        bb.g0 = bb.nb + WEsum;
        bb.g1 = bb.nb + WE_c;
        bb.g2 = bb.nb + WE_s;
        return bb;
    };

    // recurrence state: v = num * r
    float num = 0.f, r = 1.f;

    const int TU = 4;
    float xbuf[TU];
#pragma unroll
    for (int k = 0; k < TU; ++k) xbuf[k] = xin[(size_t)k * d];

    Base cur = make_base(xbuf[0]);

    for (int g = 0; g < T; g += TU) {
        float xnext[TU];
        if (g + TU < T) {
#pragma unroll
            for (int k = 0; k < TU; ++k) xnext[k] = xin[(size_t)(g + TU + k) * d];
        } else {
#pragma unroll
            for (int k = 0; k < TU; ++k) xnext[k] = 0.f;
        }

#pragma unroll
        for (int k = 0; k < TU; ++k) {
            // next timestep's base: issued BEFORE the unfolds so its 2-trans
            // chain overlaps the unfold stalls (results needed only next step)
            const float xn1 = (k + 1 < TU) ? xbuf[k + 1] : xnext[0];
            const Base nxt = make_base(xn1);

#pragma unroll
            for (int uu = 0; uu < ODE_UNFOLDS; ++uu) {
                const float cn = cmu * num;              // all parallel w/ rcp
                const float ts = A_s * num;
                const float to = A_o * num;
                const float args = fmaf(ts, r, C_s);
                const float argo = fmaf(to, r, C_o);
                const float es = __builtin_amdgcn_exp2f(args);
                const float eo = __builtin_amdgcn_exp2f(argo);
                const float ex = swap_pair(eo);

                const float t  = fmaf(cn, r, cur.nb);    // depth-1 off r
                const float c1 = fmaf(cn, r, cur.g1);
                const float c2 = fmaf(cn, r, cur.g2);
                const float n0 = fmaf(cn, r, cur.g0);

                const float P1 = fmaf(cur.Ks, es, cur.K0);
                const float P2 = fmaf(cur.db, es, cur.Kx);
                const float Q1 = fmaf(c1, es, n0);
                const float Q2 = fmaf(t,  es, c2);

                const float dsum = fmaf(P2, ex, P1);
                const float nsum = fmaf(Q2, ex, Q1);

                num = nsum;
                r = __builtin_amdgcn_rcpf(dsum);
            }

            cur = nxt;
        }

#pragma unroll
        for (int k = 0; k < TU; ++k) xbuf[k] = xnext[k];
    }

    if (h == 0) {
        const float v = num * r;
        out[(size_t)b * d + j] = fmaf(v, output_w[j], output_b[j]);
    }
}

extern "C" void kernel_launch(void* const* d_in, const int* in_sizes, int n_in,
                              void* d_out, int out_size, void* d_ws, size_t ws_size,
                              hipStream_t stream) {
    const float* inputs   = (const float*)d_in[0];
    const float* input_w  = (const float*)d_in[1];
    const float* input_b  = (const float*)d_in[2];
    const float* output_w = (const float*)d_in[3];
    const float* output_b = (const float*)d_in[4];
    const float* gleak    = (const float*)d_in[5];
    const float* vleak    = (const float*)d_in[6];
    const float* cm       = (const float*)d_in[7];
    const float* w        = (const float*)d_in[8];
    const float* mu       = (const float*)d_in[9];
    const float* sigma    = (const float*)d_in[10];
    const float* erev     = (const float*)d_in[11];
    const float* sw       = (const float*)d_in[12];
    const float* smu      = (const float*)d_in[13];
    const float* ssig     = (const float*)d_in[14];
    const float* serev    = (const float*)d_in[15];
    float* out = (float*)d_out;

    const int d = in_sizes[1];            // input_w has shape (d,)
    const int B = out_size / d;           // out is (B, d)
    const int T = in_sizes[0] / (B * d);  // inputs is (B, T, d)

    const int total = B * 2 * d;          // one thread per (b, unit)
    const int block = 64;
    const int grid = (total + block - 1) / block;
    ltc_lane_kernel<<<grid, block, 0, stream>>>(
        inputs, input_w, input_b, output_w, output_b,
        gleak, vleak, cm, w, mu, sigma, erev,
        sw, smu, ssig, serev, out, B, T, d);
}

// Round 8
// 36.158 us; speedup vs baseline: 2.0324x; 1.1424x over previous
//
#include <hip/hip_runtime.h>

#define ODE_UNFOLDS 6
#define LTC_EPS 1e-8f

// One lane per (batch b, unit u); adjacent lanes hold the coupled pair {j,j+d}.
// State: (num, r), v = num*r. Exact per-unfold algebra (num/den scaled through
// by P=(1+e_s)(1+e_x)):
//   den' = (K0 + Ks*es) + ex*(Kx + db*es)
//   num' = (n0 + c1*es) + ex*(c2 + t*es)
// t,c1,c2,n0 are single fmas off r. Full-rate VALU is packed into
// v_pk_fma_f32 via float2 ext-vectors (pair layouts chosen so no cross-half
// swizzles are needed). Finals stay scalar. Hardware rcp back on-chain
// (R6's Newton on the scaled den diverges: the (1+e_s)(1+e_x) scale factor
// moves orders of magnitude between unfolds). Base block pipelined 1 step
// ahead (R5).

typedef float v2f __attribute__((ext_vector_type(2)));

__device__ __forceinline__ float swap_pair(float x) {
    // quad_perm [1,0,3,2] : lane XOR 1, full-rate v_mov_b32 dpp
    return __int_as_float(
        __builtin_amdgcn_mov_dpp(__float_as_int(x), 0xB1, 0xF, 0xF, true));
}

struct Base {
    v2f KsDb;   // {Ks, db}
    v2f K0Kx;   // {K0, Kx}
    v2f G1Nb;   // {g1, nb}
    v2f G0G2;   // {g0, g2}
};

__global__ __launch_bounds__(64)
void ltc_lane_kernel(const float* __restrict__ inputs,
                     const float* __restrict__ input_w, const float* __restrict__ input_b,
                     const float* __restrict__ output_w, const float* __restrict__ output_b,
                     const float* __restrict__ gleak, const float* __restrict__ vleak,
                     const float* __restrict__ cm,
                     const float* __restrict__ w, const float* __restrict__ mu,
                     const float* __restrict__ sigma, const float* __restrict__ erev,
                     const float* __restrict__ sw, const float* __restrict__ smu,
                     const float* __restrict__ ssig, const float* __restrict__ serev,
                     float* __restrict__ out,
                     int B, int T, int d)
{
    const int tid = blockIdx.x * blockDim.x + threadIdx.x;
    const int units = 2 * d;
    if (tid >= B * units) return;

    const int pairIdx = tid >> 1;
    const int h = tid & 1;                 // 0 -> unit j, 1 -> unit j+d
    const int b = pairIdx / d;
    const int j = pairIdx - b * d;
    const int u  = j + h * d;              // my unit
    const int pu = j + (1 - h) * d;        // partner unit

    const float LOG2E = 1.4426950408889634f;

    // self synapse u->u
    float A_s, C_s, W_s, WE_s;
    {
        int i = u * units + u;
        float sg = sigma[i], m = mu[i];
        A_s = -sg * LOG2E; C_s = m * sg * LOG2E;
        W_s = w[i]; WE_s = W_s * erev[i];
    }
    // incoming cross synapse pu->u (partner computes its exp; we DPP it over)
    float W_c, WE_c;
    {
        int i = pu * units + u;
        W_c = w[i]; WE_c = W_c * erev[i];
    }
    // outgoing cross synapse u->pu
    float A_o, C_o;
    {
        int i = u * units + pu;
        float sg = sigma[i], m = mu[i];
        A_o = -sg * LOG2E; C_o = m * sg * LOG2E;
    }
    const float Wsum  = W_s + W_c;
    const float WEsum = WE_s + WE_c;

    // sensory synapse j -> u, input affine folded in
    float siA, siC, sW, sWE;
    {
        int i = j * units + u;
        float sg = ssig[i], m = smu[i];
        float sA = -sg * LOG2E, sC = m * sg * LOG2E;
        const float iw = input_w[j], ib = input_b[j];
        siA = iw * sA; siC = ib * sA + sC;
        sW = sw[i]; sWE = sW * serev[i];
    }

    const float cmu = cm[u] * (float)ODE_UNFOLDS;
    const float gl  = gleak[u];
    const float gv  = gl * vleak[u];
    const float den0 = cmu + gl + LTC_EPS;

    // loop-invariant pk-constant pairs
    const v2f AA2 = {A_s, A_o};            // exp slopes  (self, outgoing)
    const v2f CC2 = {C_s, C_o};            // exp offsets

    const float* __restrict__ xin = inputs + (size_t)b * T * d + j;

    auto make_base = [&](float x) -> Base {
        const float e  = __builtin_amdgcn_exp2f(fmaf(x, siA, siC));
        const float ss = __builtin_amdgcn_rcpf(1.f + e);
        const float nb = fmaf(sWE, ss, gv);
        const float db = fmaf(sW,  ss, den0);
        Base bb;
        bb.KsDb = v2f{db + W_c, db};           // {Ks, db}
        bb.K0Kx = v2f{db + Wsum, db + W_s};    // {K0, Kx}
        bb.G1Nb = v2f{nb + WE_c, nb};          // {g1, nb}
        bb.G0G2 = v2f{nb + WEsum, nb + WE_s};  // {g0, g2}
        return bb;
    };

    // recurrence state: v = num * r
    float num = 0.f, r = 1.f;

    const int TU = 4;
    float xbuf[TU];
#pragma unroll
    for (int k = 0; k < TU; ++k) xbuf[k] = xin[(size_t)k * d];

    Base cur = make_base(xbuf[0]);

    for (int g = 0; g < T; g += TU) {
        float xnext[TU];
        if (g + TU < T) {
#pragma unroll
            for (int k = 0; k < TU; ++k) xnext[k] = xin[(size_t)(g + TU + k) * d];
        } else {
#pragma unroll
            for (int k = 0; k < TU; ++k) xnext[k] = 0.f;
        }

#pragma unroll
        for (int k = 0; k < TU; ++k) {
            // next timestep's base: issued BEFORE the unfolds so its 2-trans
            // chain overlaps unfold stalls (results needed only next step)
            const float xn1 = (k + 1 < TU) ? xbuf[k + 1] : xnext[0];
            const Base nxt = make_base(xn1);

#pragma unroll
            for (int uu = 0; uu < ODE_UNFOLDS; ++uu) {
                const float cn = cmu * num;              // parallel w/ rcp
                const v2f NN = {num, num};
                const v2f RR = {r, r};

                // both exp args in one pk_fma: {A_s*num, A_o*num}*r + {C_s,C_o}
                const v2f ts2   = AA2 * NN;
                const v2f args2 = __builtin_elementwise_fma(ts2, RR, CC2);

                const float es = __builtin_amdgcn_exp2f(args2.x);
                const float eo = __builtin_amdgcn_exp2f(args2.y);
                const float ex = swap_pair(eo);          // partner's exp (late)

                const v2f CN2 = {cn, cn};
                const v2f t_c1  = __builtin_elementwise_fma(CN2, RR, cur.G1Nb); // {c1, t}
                const v2f c2_n0 = __builtin_elementwise_fma(CN2, RR, cur.G0G2); // {n0, c2}

                const v2f ES2 = {es, es};
                const v2f Pv = __builtin_elementwise_fma(cur.KsDb, ES2, cur.K0Kx); // {P1, P2}
                const v2f Qv = __builtin_elementwise_fma(t_c1,    ES2, c2_n0);     // {Q1, Q2}

                // depth-1 finals in ex (scalar: halves read free)
                const float dsum = fmaf(Pv.y, ex, Pv.x);
                const float nsum = fmaf(Qv.y, ex, Qv.x);

                num = nsum;
                r = __builtin_amdgcn_rcpf(dsum);
            }

            cur = nxt;
        }

#pragma unroll
        for (int k = 0; k < TU; ++k) xbuf[k] = xnext[k];
    }

    if (h == 0) {
        const float v = num * r;
        out[(size_t)b * d + j] = fmaf(v, output_w[j], output_b[j]);
    }
}

extern "C" void kernel_launch(void* const* d_in, const int* in_sizes, int n_in,
                              void* d_out, int out_size, void* d_ws, size_t ws_size,
                              hipStream_t stream) {
    const float* inputs   = (const float*)d_in[0];
    const float* input_w  = (const float*)d_in[1];
    const float* input_b  = (const float*)d_in[2];
    const float* output_w = (const float*)d_in[3];
    const float* output_b = (const float*)d_in[4];
    const float* gleak    = (const float*)d_in[5];
    const float* vleak    = (const float*)d_in[6];
    const float* cm       = (const float*)d_in[7];
    const float* w        = (const float*)d_in[8];
    const float* mu       = (const float*)d_in[9];
    const float* sigma    = (const float*)d_in[10];
    const float* erev     = (const float*)d_in[11];
    const float* sw       = (const float*)d_in[12];
    const float* smu      = (const float*)d_in[13];
    const float* ssig     = (const float*)d_in[14];
    const float* serev    = (const float*)d_in[15];
    float* out = (float*)d_out;

    const int d = in_sizes[1];            // input_w has shape (d,)
    const int B = out_size / d;           // out is (B, d)
    const int T = in_sizes[0] / (B * d);  // inputs is (B, T, d)

    const int total = B * 2 * d;          // one thread per (b, unit)
    const int block = 64;
    const int grid = (total + block - 1) / block;
    ltc_lane_kernel<<<grid, block, 0, stream>>>(
        inputs, input_w, input_b, output_w, output_b,
        gleak, vleak, cm, w, mu, sigma, erev,
        sw, smu, ssig, serev, out, B, T, d);
}